// Round 1
// baseline (917.088 us; speedup 1.0000x reference)
//
#include <hip/hip_runtime.h>

#define IN_F 512
#define HID_F 256
#define LAT_F 128

// ---------------- degree / norm ----------------

__global__ void init_nodes(float* deg, int* counts, int* fill, int N) {
    int i = blockIdx.x * 256 + threadIdx.x;
    if (i < N) { deg[i] = 1.0f; counts[i] = 1; fill[i] = 0; }  // self-loop contributes w=1 and one in-edge
}

__global__ void edge_deg(const int* __restrict__ ei, const float* __restrict__ attr,
                         float* deg, int* counts, int E) {
    int e = blockIdx.x * 256 + threadIdx.x;
    if (e < E) {
        int d = ei[E + e];           // edge_index[1][e] = dst
        atomicAdd(&deg[d], attr[e]);
        atomicAdd(&counts[d], 1);
    }
}

__global__ void node_dis(const float* __restrict__ deg, float* dis, int N) {
    int i = blockIdx.x * 256 + threadIdx.x;
    if (i < N) {
        float dg = deg[i];
        dis[i] = dg > 0.f ? rsqrtf(fmaxf(dg, 1e-12f)) : 0.f;
    }
}

// ---------------- exclusive scan (counts -> row_ptr) ----------------

__global__ void scan_blocks(const int* __restrict__ counts, int* __restrict__ excl,
                            int* __restrict__ blockSums, int N) {
    __shared__ int sdata[256];
    int tid = threadIdx.x;
    int base = blockIdx.x * 1024 + tid * 4;
    int v[4]; int sum = 0;
#pragma unroll
    for (int j = 0; j < 4; ++j) { v[j] = (base + j < N) ? counts[base + j] : 0; sum += v[j]; }
    sdata[tid] = sum;
    __syncthreads();
    for (int off = 1; off < 256; off <<= 1) {
        int t = (tid >= off) ? sdata[tid - off] : 0;
        __syncthreads();
        sdata[tid] += t;
        __syncthreads();
    }
    if (tid == 255) blockSums[blockIdx.x] = sdata[255];
    int run = sdata[tid] - sum;  // exclusive prefix of this thread's chunk
#pragma unroll
    for (int j = 0; j < 4; ++j) { if (base + j < N) excl[base + j] = run; run += v[j]; }
}

__global__ void scan_sums(int* blockSums, int NB) {  // NB <= 64, one wave
    __shared__ int s[64];
    int tid = threadIdx.x;
    int v = (tid < NB) ? blockSums[tid] : 0;
    s[tid] = v;
    __syncthreads();
    for (int off = 1; off < 64; off <<= 1) {
        int t = (tid >= off) ? s[tid - off] : 0;
        __syncthreads();
        s[tid] += t;
        __syncthreads();
    }
    if (tid < NB) blockSums[tid] = s[tid] - v;  // exclusive
}

__global__ void scan_add(int* row_ptr, const int* __restrict__ blockSums, int N, int total) {
    int tid = threadIdx.x;
    int base = blockIdx.x * 1024 + tid * 4;
    int add = blockSums[blockIdx.x];
#pragma unroll
    for (int j = 0; j < 4; ++j) if (base + j < N) row_ptr[base + j] += add;
    if (blockIdx.x == 0 && tid == 0) row_ptr[N] = total;
}

// ---------------- CSR fill (edges + self loops) ----------------

__global__ void fill_csr(const int* __restrict__ ei, const float* __restrict__ attr,
                         const float* __restrict__ dis, const int* __restrict__ row_ptr,
                         int* fill, int* col, float* val, int E, int N) {
    int e = blockIdx.x * 256 + threadIdx.x;
    if (e >= E + N) return;
    int s, d; float w;
    if (e < E) { s = ei[e]; d = ei[E + e]; w = attr[e]; }
    else       { s = d = e - E; w = 1.0f; }
    int pos = row_ptr[d] + atomicAdd(&fill[d], 1);
    col[pos] = s;
    val[pos] = dis[s] * w * dis[d];
}

// ---------------- fused B2 = [W_mu | W_lv] ----------------

__global__ void build_b2(const float* __restrict__ Wmu, const float* __restrict__ Wlv, float* B2) {
    int t = blockIdx.x * 256 + threadIdx.x;   // HID_F*HID_F threads
    int k = t >> 8, j = t & 255;
    B2[t] = (j < 128) ? Wmu[k * 128 + j] : Wlv[k * 128 + (j - 128)];
}

// ---------------- fp32 SGEMM: C[M,Nc] = A[M,K] @ B[K,Nc] ----------------
// BM=BN=64, BK=16, 256 threads, 4x4 per thread. Nc%64==0, K%16==0 required.

#define BM 64
#define BN 64
#define BK 16

__global__ __launch_bounds__(256) void sgemm(const float* __restrict__ A, const float* __restrict__ B,
                                             float* __restrict__ C, int M, int Nc, int K) {
    __shared__ float As[BK][BM + 4];   // +4 pad keeps float4 alignment (68*4=272B rows)
    __shared__ float Bs[BK][BN];
    int tid = threadIdx.x;
    int tx = tid & 15, ty = tid >> 4;
    int rowBase = blockIdx.y * BM, colBase = blockIdx.x * BN;
    float acc[4][4] = {};
    for (int k0 = 0; k0 < K; k0 += BK) {
        // A tile: 64 rows x 16 k, each thread loads float4 along k
        int r = tid >> 2, kk = (tid & 3) << 2;
        int row = rowBase + r;
        float4 va = make_float4(0.f, 0.f, 0.f, 0.f);
        if (row < M) va = *(const float4*)(A + (size_t)row * K + k0 + kk);
        As[kk + 0][r] = va.x; As[kk + 1][r] = va.y; As[kk + 2][r] = va.z; As[kk + 3][r] = va.w;
        // B tile: 16 k x 64 cols
        int bk = tid >> 4, bc = (tid & 15) << 2;
        *(float4*)&Bs[bk][bc] = *(const float4*)(B + (size_t)(k0 + bk) * Nc + colBase + bc);
        __syncthreads();
#pragma unroll
        for (int k = 0; k < BK; ++k) {
            float4 a4 = *(const float4*)&As[k][ty << 2];
            float4 b4 = *(const float4*)&Bs[k][tx << 2];
            float av[4] = {a4.x, a4.y, a4.z, a4.w};
            float bv[4] = {b4.x, b4.y, b4.z, b4.w};
#pragma unroll
            for (int i2 = 0; i2 < 4; ++i2)
#pragma unroll
                for (int j2 = 0; j2 < 4; ++j2)
                    acc[i2][j2] = fmaf(av[i2], bv[j2], acc[i2][j2]);
        }
        __syncthreads();
    }
#pragma unroll
    for (int i2 = 0; i2 < 4; ++i2) {
        int row = rowBase + (ty << 2) + i2;
        if (row < M) {
            float4 o = make_float4(acc[i2][0], acc[i2][1], acc[i2][2], acc[i2][3]);
            *(float4*)(C + (size_t)row * Nc + colBase + (tx << 2)) = o;
        }
    }
}

// ---------------- aggregation (gather, CSR) ----------------

__global__ void agg_relu(const float* __restrict__ m, const int* __restrict__ row_ptr,
                         const int* __restrict__ col, const float* __restrict__ val,
                         const float* __restrict__ bias, float* __restrict__ out) {
    int i = blockIdx.x, c = threadIdx.x;   // 256 threads = 256 features
    int p0 = row_ptr[i], p1 = row_ptr[i + 1];
    float acc = 0.f;
    for (int p = p0; p < p1; ++p) {
        int s = col[p]; float w = val[p];   // uniform across block -> scalar loads
        acc = fmaf(m[(size_t)s * HID_F + c], w, acc);
    }
    acc += bias[c];
    out[(size_t)i * HID_F + c] = acc > 0.f ? acc : 0.f;
}

__global__ void agg_out(const float* __restrict__ m, const int* __restrict__ row_ptr,
                        const int* __restrict__ col, const float* __restrict__ val,
                        const float* __restrict__ bmu, const float* __restrict__ blv,
                        float* __restrict__ out, int N) {
    int i = blockIdx.x, c = threadIdx.x;
    int p0 = row_ptr[i], p1 = row_ptr[i + 1];
    float acc = 0.f;
    for (int p = p0; p < p1; ++p) {
        int s = col[p]; float w = val[p];
        acc = fmaf(m[(size_t)s * HID_F + c], w, acc);
    }
    if (c < LAT_F) out[(size_t)i * LAT_F + c] = acc + bmu[c];                       // mu
    else           out[(size_t)(N + i) * LAT_F + (c - LAT_F)] = acc + blv[c - LAT_F]; // logvar
}

// ---------------- launch ----------------

extern "C" void kernel_launch(void* const* d_in, const int* in_sizes, int n_in,
                              void* d_out, int out_size, void* d_ws, size_t ws_size,
                              hipStream_t stream) {
    const float* x    = (const float*)d_in[0];
    const int*   ei   = (const int*)d_in[1];
    const float* attr = (const float*)d_in[2];
    const float* W1   = (const float*)d_in[3];
    const float* b1   = (const float*)d_in[4];
    const float* Wmu  = (const float*)d_in[5];
    const float* bmu  = (const float*)d_in[6];
    const float* Wlv  = (const float*)d_in[7];
    const float* blv  = (const float*)d_in[8];
    float* out = (float*)d_out;

    const int N  = in_sizes[0] / IN_F;   // 50000
    const int E  = in_sizes[2];          // 800000
    const int EN = E + N;

    char* w = (char*)d_ws;
    size_t off = 0;
    auto carve = [&](size_t bytes) -> void* {
        void* p = w + off; off += (bytes + 255) & ~(size_t)255; return p;
    };
    float* deg       = (float*)carve((size_t)N * 4);
    float* dis       = (float*)carve((size_t)N * 4);
    int*   counts    = (int*)  carve((size_t)N * 4);
    int*   fill      = (int*)  carve((size_t)N * 4);
    int*   row_ptr   = (int*)  carve((size_t)(N + 1) * 4);
    int*   blockSums = (int*)  carve(64 * 4);
    int*   col       = (int*)  carve((size_t)EN * 4);
    float* val       = (float*)carve((size_t)EN * 4);
    float* B2        = (float*)carve((size_t)HID_F * HID_F * 4);
    float* m         = (float*)carve((size_t)N * HID_F * 4);   // m1, reused as m2
    float* hidden    = (float*)carve((size_t)N * HID_F * 4);

    int nb256 = (N + 255) / 256;
    init_nodes<<<nb256, 256, 0, stream>>>(deg, counts, fill, N);
    edge_deg<<<(E + 255) / 256, 256, 0, stream>>>(ei, attr, deg, counts, E);
    node_dis<<<nb256, 256, 0, stream>>>(deg, dis, N);

    int NB = (N + 1023) / 1024;   // 49 <= 64
    scan_blocks<<<NB, 256, 0, stream>>>(counts, row_ptr, blockSums, N);
    scan_sums<<<1, 64, 0, stream>>>(blockSums, NB);
    scan_add<<<NB, 256, 0, stream>>>(row_ptr, blockSums, N, EN);

    fill_csr<<<(EN + 255) / 256, 256, 0, stream>>>(ei, attr, dis, row_ptr, fill, col, val, E, N);
    build_b2<<<(HID_F * HID_F + 255) / 256, 256, 0, stream>>>(Wmu, Wlv, B2);

    // m1 = x @ W1   [50000,512]x[512,256]
    sgemm<<<dim3(HID_F / BN, (N + BM - 1) / BM), 256, 0, stream>>>(x, W1, m, N, HID_F, IN_F);
    // hidden = relu(A_hat * m1 + b1)
    agg_relu<<<N, HID_F, 0, stream>>>(m, row_ptr, col, val, b1, hidden);
    // m2 = hidden @ [W_mu | W_lv]   [50000,256]x[256,256]
    sgemm<<<dim3(HID_F / BN, (N + BM - 1) / BM), 256, 0, stream>>>(hidden, B2, m, N, HID_F, HID_F);
    // (mu|logvar) = A_hat * m2 + (b_mu|b_lv)  -> directly into d_out
    agg_out<<<N, HID_F, 0, stream>>>(m, row_ptr, col, val, bmu, blv, out, N);
}

// Round 2
// 534.722 us; speedup vs baseline: 1.7151x; 1.7151x over previous
//
#include <hip/hip_runtime.h>

#define IN_F 512
#define HID_F 256
#define LAT_F 128

typedef __bf16 bf16x8 __attribute__((ext_vector_type(8)));
typedef float floatx4 __attribute__((ext_vector_type(4)));

__device__ __forceinline__ unsigned short f2bf(float f) {
    union { float f; unsigned u; } v; v.f = f;
    unsigned r = (v.u + 0x7fff + ((v.u >> 16) & 1)) >> 16;
    return (unsigned short)r;
}
__device__ __forceinline__ float bf2f(unsigned short h) {
    union { unsigned u; float f; } v; v.u = ((unsigned)h) << 16;
    return v.f;
}

// ---------------- degree / norm ----------------

__global__ void init_nodes(float* deg, int* counts, int* fill, int N) {
    int i = blockIdx.x * 256 + threadIdx.x;
    if (i < N) { deg[i] = 1.0f; counts[i] = 1; fill[i] = 0; }
}

__global__ void edge_deg(const int* __restrict__ ei, const float* __restrict__ attr,
                         float* deg, int* counts, int E) {
    int e = blockIdx.x * 256 + threadIdx.x;
    if (e < E) {
        int d = ei[E + e];
        atomicAdd(&deg[d], attr[e]);
        atomicAdd(&counts[d], 1);
    }
}

__global__ void node_dis(const float* __restrict__ deg, float* dis, int N) {
    int i = blockIdx.x * 256 + threadIdx.x;
    if (i < N) {
        float dg = deg[i];
        dis[i] = dg > 0.f ? rsqrtf(fmaxf(dg, 1e-12f)) : 0.f;
    }
}

// ---------------- exclusive scan (counts -> row_ptr) ----------------

__global__ void scan_blocks(const int* __restrict__ counts, int* __restrict__ excl,
                            int* __restrict__ blockSums, int N) {
    __shared__ int sdata[256];
    int tid = threadIdx.x;
    int base = blockIdx.x * 1024 + tid * 4;
    int v[4]; int sum = 0;
#pragma unroll
    for (int j = 0; j < 4; ++j) { v[j] = (base + j < N) ? counts[base + j] : 0; sum += v[j]; }
    sdata[tid] = sum;
    __syncthreads();
    for (int off = 1; off < 256; off <<= 1) {
        int t = (tid >= off) ? sdata[tid - off] : 0;
        __syncthreads();
        sdata[tid] += t;
        __syncthreads();
    }
    if (tid == 255) blockSums[blockIdx.x] = sdata[255];
    int run = sdata[tid] - sum;
#pragma unroll
    for (int j = 0; j < 4; ++j) { if (base + j < N) excl[base + j] = run; run += v[j]; }
}

__global__ void scan_sums(int* blockSums, int NB) {
    __shared__ int s[64];
    int tid = threadIdx.x;
    int v = (tid < NB) ? blockSums[tid] : 0;
    s[tid] = v;
    __syncthreads();
    for (int off = 1; off < 64; off <<= 1) {
        int t = (tid >= off) ? s[tid - off] : 0;
        __syncthreads();
        s[tid] += t;
        __syncthreads();
    }
    if (tid < NB) blockSums[tid] = s[tid] - v;
}

__global__ void scan_add(int* row_ptr, const int* __restrict__ blockSums, int N, int total) {
    int tid = threadIdx.x;
    int base = blockIdx.x * 1024 + tid * 4;
    int add = blockSums[blockIdx.x];
#pragma unroll
    for (int j = 0; j < 4; ++j) if (base + j < N) row_ptr[base + j] += add;
    if (blockIdx.x == 0 && tid == 0) row_ptr[N] = total;
}

// ---------------- CSR fill (edges + self loops) ----------------

__global__ void fill_csr(const int* __restrict__ ei, const float* __restrict__ attr,
                         const float* __restrict__ dis, const int* __restrict__ row_ptr,
                         int* fill, int* col, float* val, int E, int N) {
    int e = blockIdx.x * 256 + threadIdx.x;
    if (e >= E + N) return;
    int s, d; float w;
    if (e < E) { s = ei[e]; d = ei[E + e]; w = attr[e]; }
    else       { s = d = e - E; w = 1.0f; }
    int pos = row_ptr[d] + atomicAdd(&fill[d], 1);
    col[pos] = s;
    val[pos] = dis[s] * w * dis[d];
}

// ---------------- weight prep: transpose + bf16 ----------------
// W1t[n][k] = bf16(W1[k][n]);  n<256, k<512
__global__ void prep_w1(const float* __restrict__ W1, unsigned short* __restrict__ W1t) {
    int t = blockIdx.x * 256 + threadIdx.x;   // 256*512 threads
    int n = t >> 9, k = t & 511;
    W1t[t] = f2bf(W1[(size_t)k * HID_F + n]);
}
// B2t[n][k]: n<256 (mu cols 0..127, lv cols 128..255), k<256
__global__ void prep_b2(const float* __restrict__ Wmu, const float* __restrict__ Wlv,
                        unsigned short* __restrict__ B2t) {
    int t = blockIdx.x * 256 + threadIdx.x;   // 256*256 threads
    int n = t >> 8, k = t & 255;
    float v = (n < 128) ? Wmu[(size_t)k * LAT_F + n] : Wlv[(size_t)k * LAT_F + (n - 128)];
    B2t[t] = f2bf(v);
}

// ---------------- MFMA bf16 GEMM: C[M,256] = A[M,K] @ B[K,256], C bf16 ----------------
// Bt is pre-transposed bf16 [256][K] (n-major, k contiguous).
// BM=64, BN=256 (full), BK=32. 256 threads = 4 waves; wave w owns rows w*16..w*16+15.

#define LDA 40  // padded row stride (halfwords) for 16B alignment + 2-way-max conflicts

template <bool ABF16>
__global__ __launch_bounds__(256) void gemm_mfma(const void* __restrict__ Avoid,
                                                 const unsigned short* __restrict__ Bt,
                                                 unsigned short* __restrict__ C,
                                                 int M, int K) {
    __shared__ unsigned short As[64][LDA];
    __shared__ unsigned short Bs[256][LDA];
    int tid = threadIdx.x;
    int wave = tid >> 6, lane = tid & 63;
    int mrow = lane & 15, quad = lane >> 4;
    int blockRow = blockIdx.x * 64;

    floatx4 acc[16];
#pragma unroll
    for (int i = 0; i < 16; ++i) acc[i] = (floatx4){0.f, 0.f, 0.f, 0.f};

    int r = tid >> 2;            // 0..63  (A stage row / B stage col-div)
    int kk = (tid & 3) << 3;     // 0,8,16,24 (k offset in halfwords)

    for (int k0 = 0; k0 < K; k0 += 32) {
        // ---- stage A tile (64 x 32) ----
        int arow = blockRow + r;
        if (ABF16) {
            const unsigned short* A = (const unsigned short*)Avoid;
            uint4 u = make_uint4(0, 0, 0, 0);
            if (arow < M) u = *(const uint4*)(A + (size_t)arow * K + k0 + kk);
            *(uint4*)&As[r][kk] = u;
        } else {
            const float* A = (const float*)Avoid;
            float4 a0 = make_float4(0, 0, 0, 0), a1 = a0;
            if (arow < M) {
                const float* p = A + (size_t)arow * K + k0 + kk;
                a0 = *(const float4*)p; a1 = *(const float4*)(p + 4);
            }
            unsigned short h[8] = {f2bf(a0.x), f2bf(a0.y), f2bf(a0.z), f2bf(a0.w),
                                   f2bf(a1.x), f2bf(a1.y), f2bf(a1.z), f2bf(a1.w)};
            *(uint4*)&As[r][kk] = *(uint4*)h;
        }
        // ---- stage B tile (256 x 32), 4 passes of 64 cols ----
#pragma unroll
        for (int pass = 0; pass < 4; ++pass) {
            int bcol = r + pass * 64;
            uint4 u = *(const uint4*)(Bt + (size_t)bcol * K + k0 + kk);
            *(uint4*)&Bs[bcol][kk] = u;
        }
        __syncthreads();
        // ---- compute ----
        bf16x8 afrag = *(const bf16x8*)&As[wave * 16 + mrow][quad << 3];
#pragma unroll
        for (int ct = 0; ct < 16; ++ct) {
            bf16x8 bfrag = *(const bf16x8*)&Bs[ct * 16 + mrow][quad << 3];
            acc[ct] = __builtin_amdgcn_mfma_f32_16x16x32_bf16(afrag, bfrag, acc[ct], 0, 0, 0);
        }
        __syncthreads();
    }
    // ---- epilogue: C/D layout col=lane&15, row=quad*4+i ----
#pragma unroll
    for (int ct = 0; ct < 16; ++ct) {
        int colo = ct * 16 + mrow;
#pragma unroll
        for (int i = 0; i < 4; ++i) {
            int row = blockRow + wave * 16 + quad * 4 + i;
            if (row < M) C[(size_t)row * HID_F + colo] = f2bf(acc[ct][i]);
        }
    }
}

// ---------------- aggregation (gather, CSR), bf16 m, fp32 accumulate ----------------
// 64 threads/block; lane l owns features 4l..4l+3.

__global__ void agg_relu(const unsigned short* __restrict__ m, const int* __restrict__ row_ptr,
                         const int* __restrict__ col, const float* __restrict__ val,
                         const float* __restrict__ bias, unsigned short* __restrict__ hidden) {
    int i = blockIdx.x, l = threadIdx.x, c0 = l << 2;
    int p0 = row_ptr[i], p1 = row_ptr[i + 1];
    float a0 = 0.f, a1 = 0.f, a2 = 0.f, a3 = 0.f;
    for (int p = p0; p < p1; ++p) {
        int s = col[p]; float w = val[p];
        ushort4 u = *(const ushort4*)(m + (size_t)s * HID_F + c0);
        a0 = fmaf(bf2f(u.x), w, a0);
        a1 = fmaf(bf2f(u.y), w, a1);
        a2 = fmaf(bf2f(u.z), w, a2);
        a3 = fmaf(bf2f(u.w), w, a3);
    }
    float4 b = *(const float4*)(bias + c0);
    a0 = fmaxf(a0 + b.x, 0.f); a1 = fmaxf(a1 + b.y, 0.f);
    a2 = fmaxf(a2 + b.z, 0.f); a3 = fmaxf(a3 + b.w, 0.f);
    ushort4 o = make_ushort4(f2bf(a0), f2bf(a1), f2bf(a2), f2bf(a3));
    *(ushort4*)(hidden + (size_t)i * HID_F + c0) = o;
}

__global__ void agg_out(const unsigned short* __restrict__ m, const int* __restrict__ row_ptr,
                        const int* __restrict__ col, const float* __restrict__ val,
                        const float* __restrict__ bmu, const float* __restrict__ blv,
                        float* __restrict__ out, int N) {
    int i = blockIdx.x, l = threadIdx.x, c0 = l << 2;
    int p0 = row_ptr[i], p1 = row_ptr[i + 1];
    float a0 = 0.f, a1 = 0.f, a2 = 0.f, a3 = 0.f;
    for (int p = p0; p < p1; ++p) {
        int s = col[p]; float w = val[p];
        ushort4 u = *(const ushort4*)(m + (size_t)s * HID_F + c0);
        a0 = fmaf(bf2f(u.x), w, a0);
        a1 = fmaf(bf2f(u.y), w, a1);
        a2 = fmaf(bf2f(u.z), w, a2);
        a3 = fmaf(bf2f(u.w), w, a3);
    }
    if (l < 32) {
        float4 b = *(const float4*)(bmu + c0);
        float4 o = make_float4(a0 + b.x, a1 + b.y, a2 + b.z, a3 + b.w);
        *(float4*)(out + (size_t)i * LAT_F + c0) = o;
    } else {
        int c = c0 - 128;
        float4 b = *(const float4*)(blv + c);
        float4 o = make_float4(a0 + b.x, a1 + b.y, a2 + b.z, a3 + b.w);
        *(float4*)(out + (size_t)(N + i) * LAT_F + c) = o;
    }
}

// ---------------- launch ----------------

extern "C" void kernel_launch(void* const* d_in, const int* in_sizes, int n_in,
                              void* d_out, int out_size, void* d_ws, size_t ws_size,
                              hipStream_t stream) {
    const float* x    = (const float*)d_in[0];
    const int*   ei   = (const int*)d_in[1];
    const float* attr = (const float*)d_in[2];
    const float* W1   = (const float*)d_in[3];
    const float* b1   = (const float*)d_in[4];
    const float* Wmu  = (const float*)d_in[5];
    const float* bmu  = (const float*)d_in[6];
    const float* Wlv  = (const float*)d_in[7];
    const float* blv  = (const float*)d_in[8];
    float* out = (float*)d_out;

    const int N  = in_sizes[0] / IN_F;   // 50000
    const int E  = in_sizes[2];          // 800000
    const int EN = E + N;

    char* w = (char*)d_ws;
    size_t off = 0;
    auto carve = [&](size_t bytes) -> void* {
        void* p = w + off; off += (bytes + 255) & ~(size_t)255; return p;
    };
    float*          deg       = (float*)carve((size_t)N * 4);
    float*          dis       = (float*)carve((size_t)N * 4);
    int*            counts    = (int*)  carve((size_t)N * 4);
    int*            fill      = (int*)  carve((size_t)N * 4);
    int*            row_ptr   = (int*)  carve((size_t)(N + 1) * 4);
    int*            blockSums = (int*)  carve(64 * 4);
    int*            col       = (int*)  carve((size_t)EN * 4);
    float*          val       = (float*)carve((size_t)EN * 4);
    unsigned short* W1t       = (unsigned short*)carve((size_t)HID_F * IN_F * 2);
    unsigned short* B2t       = (unsigned short*)carve((size_t)HID_F * HID_F * 2);
    unsigned short* m         = (unsigned short*)carve((size_t)N * HID_F * 2);  // m1, reused as m2
    unsigned short* hidden    = (unsigned short*)carve((size_t)N * HID_F * 2);

    int nb256 = (N + 255) / 256;
    init_nodes<<<nb256, 256, 0, stream>>>(deg, counts, fill, N);
    edge_deg<<<(E + 255) / 256, 256, 0, stream>>>(ei, attr, deg, counts, E);
    node_dis<<<nb256, 256, 0, stream>>>(deg, dis, N);

    int NB = (N + 1023) / 1024;
    scan_blocks<<<NB, 256, 0, stream>>>(counts, row_ptr, blockSums, N);
    scan_sums<<<1, 64, 0, stream>>>(blockSums, NB);
    scan_add<<<NB, 256, 0, stream>>>(row_ptr, blockSums, N, EN);

    fill_csr<<<(EN + 255) / 256, 256, 0, stream>>>(ei, attr, dis, row_ptr, fill, col, val, E, N);

    prep_w1<<<(HID_F * IN_F + 255) / 256, 256, 0, stream>>>(W1, W1t);
    prep_b2<<<(HID_F * HID_F + 255) / 256, 256, 0, stream>>>(Wmu, Wlv, B2t);

    int gblocks = (N + 63) / 64;
    // m1 = bf16(x) @ W1   [50000,512]x[512,256] -> bf16
    gemm_mfma<false><<<gblocks, 256, 0, stream>>>(x, W1t, m, N, IN_F);
    // hidden = relu(A_hat * m1 + b1) -> bf16
    agg_relu<<<N, 64, 0, stream>>>(m, row_ptr, col, val, b1, hidden);
    // m2 = hidden @ [W_mu | W_lv]   [50000,256]x[256,256] -> bf16
    gemm_mfma<true><<<gblocks, 256, 0, stream>>>(hidden, B2t, m, N, HID_F);
    // (mu|logvar) = A_hat * m2 + (b_mu|b_lv) -> fp32 d_out
    agg_out<<<N, 64, 0, stream>>>(m, row_ptr, col, val, bmu, blv, out, N);
}

// Round 3
// 502.010 us; speedup vs baseline: 1.8268x; 1.0652x over previous
//
#include <hip/hip_runtime.h>

#define IN_F 512
#define HID_F 256
#define LAT_F 128

typedef __bf16 bf16x8 __attribute__((ext_vector_type(8)));
typedef float floatx4 __attribute__((ext_vector_type(4)));

__device__ __forceinline__ unsigned short f2bf(float f) {
    union { float f; unsigned u; } v; v.f = f;
    unsigned r = (v.u + 0x7fff + ((v.u >> 16) & 1)) >> 16;
    return (unsigned short)r;
}
__device__ __forceinline__ float bf2f(unsigned short h) {
    union { unsigned u; float f; } v; v.u = ((unsigned)h) << 16;
    return v.f;
}

// async 16B global -> LDS DMA (dest = wave-uniform base + lane*16)
__device__ __forceinline__ void gload_lds16(const void* g, void* lds) {
    __builtin_amdgcn_global_load_lds(
        (const __attribute__((address_space(1))) unsigned int*)(uintptr_t)g,
        (__attribute__((address_space(3))) unsigned int*)(uintptr_t)lds,
        16, 0, 0);
}

// ---------------- degree / norm ----------------

__global__ void init_nodes(float* deg, int* counts, int* fill, int N) {
    int i = blockIdx.x * 256 + threadIdx.x;
    if (i < N) { deg[i] = 1.0f; counts[i] = 1; fill[i] = 0; }
}

__global__ void edge_deg(const int* __restrict__ ei, const float* __restrict__ attr,
                         float* deg, int* counts, int E) {
    int e = blockIdx.x * 256 + threadIdx.x;
    if (e < E) {
        int d = ei[E + e];
        atomicAdd(&deg[d], attr[e]);
        atomicAdd(&counts[d], 1);
    }
}

__global__ void node_dis(const float* __restrict__ deg, float* dis, int N) {
    int i = blockIdx.x * 256 + threadIdx.x;
    if (i < N) {
        float dg = deg[i];
        dis[i] = dg > 0.f ? rsqrtf(fmaxf(dg, 1e-12f)) : 0.f;
    }
}

// ---------------- exclusive scan (counts -> row_ptr) ----------------

__global__ void scan_blocks(const int* __restrict__ counts, int* __restrict__ excl,
                            int* __restrict__ blockSums, int N) {
    __shared__ int sdata[256];
    int tid = threadIdx.x;
    int base = blockIdx.x * 1024 + tid * 4;
    int v[4]; int sum = 0;
#pragma unroll
    for (int j = 0; j < 4; ++j) { v[j] = (base + j < N) ? counts[base + j] : 0; sum += v[j]; }
    sdata[tid] = sum;
    __syncthreads();
    for (int off = 1; off < 256; off <<= 1) {
        int t = (tid >= off) ? sdata[tid - off] : 0;
        __syncthreads();
        sdata[tid] += t;
        __syncthreads();
    }
    if (tid == 255) blockSums[blockIdx.x] = sdata[255];
    int run = sdata[tid] - sum;
#pragma unroll
    for (int j = 0; j < 4; ++j) { if (base + j < N) excl[base + j] = run; run += v[j]; }
}

__global__ void scan_sums(int* blockSums, int NB) {
    __shared__ int s[64];
    int tid = threadIdx.x;
    int v = (tid < NB) ? blockSums[tid] : 0;
    s[tid] = v;
    __syncthreads();
    for (int off = 1; off < 64; off <<= 1) {
        int t = (tid >= off) ? s[tid - off] : 0;
        __syncthreads();
        s[tid] += t;
        __syncthreads();
    }
    if (tid < NB) blockSums[tid] = s[tid] - v;
}

__global__ void scan_add(int* row_ptr, const int* __restrict__ blockSums, int N, int total) {
    int tid = threadIdx.x;
    int base = blockIdx.x * 1024 + tid * 4;
    int add = blockSums[blockIdx.x];
#pragma unroll
    for (int j = 0; j < 4; ++j) if (base + j < N) row_ptr[base + j] += add;
    if (blockIdx.x == 0 && tid == 0) row_ptr[N] = total;
}

// ---------------- CSR fill (edges + self loops) ----------------

__global__ void fill_csr(const int* __restrict__ ei, const float* __restrict__ attr,
                         const float* __restrict__ dis, const int* __restrict__ row_ptr,
                         int* fill, int* col, float* val, int E, int N) {
    int e = blockIdx.x * 256 + threadIdx.x;
    if (e >= E + N) return;
    int s, d; float w;
    if (e < E) { s = ei[e]; d = ei[E + e]; w = attr[e]; }
    else       { s = d = e - E; w = 1.0f; }
    int pos = row_ptr[d] + atomicAdd(&fill[d], 1);
    col[pos] = s;
    val[pos] = dis[s] * w * dis[d];
}

// ---------------- weight prep: transpose + bf16 ----------------
__global__ void prep_w1(const float* __restrict__ W1, unsigned short* __restrict__ W1t) {
    int t = blockIdx.x * 256 + threadIdx.x;   // 256*512 threads
    int n = t >> 9, k = t & 511;
    W1t[t] = f2bf(W1[(size_t)k * HID_F + n]);
}
__global__ void prep_b2(const float* __restrict__ Wmu, const float* __restrict__ Wlv,
                        unsigned short* __restrict__ B2t) {
    int t = blockIdx.x * 256 + threadIdx.x;   // 256*256 threads
    int n = t >> 8, k = t & 255;
    float v = (n < 128) ? Wmu[(size_t)k * LAT_F + n] : Wlv[(size_t)k * LAT_F + (n - 128)];
    B2t[t] = f2bf(v);
}

// ---------------- MFMA bf16 GEMM: C[M,256] = A[M,K] @ Bt[256,K]^T, C bf16 ----------------
// m97-style: BM=64, BN=256, BK=32; 4 waves; wave w owns 64 rows x cols [64w,64w+64).
// 4x4 grid of 16x16x32 tiles per wave: 16 MFMA from 8 ds_read_b128 per k-step.
// LDS K-major unpadded (required by global_load_lds lane layout).

template <bool ABF16>
__global__ __launch_bounds__(256) void gemm_mfma(const void* __restrict__ Avoid,
                                                 const unsigned short* __restrict__ Bt,
                                                 unsigned short* __restrict__ C,
                                                 int M, int K) {
    __shared__ unsigned short As[64 * 32];    // 4 KB
    __shared__ unsigned short Bs[256 * 32];   // 16 KB
    int tid = threadIdx.x;
    int wave = tid >> 6, lane = tid & 63;
    int mrow = lane & 15, quad = lane >> 4;
    int blockRow = blockIdx.x * 64;

    floatx4 acc[4][4];
#pragma unroll
    for (int i = 0; i < 4; ++i)
#pragma unroll
        for (int j = 0; j < 4; ++j) acc[i][j] = (floatx4){0.f, 0.f, 0.f, 0.f};

    int r = tid >> 2;            // 0..63 : A row / B col-mod-64
    int kq = tid & 3;            // 16B chunk within the 32-halfword k-slab
    int arow = blockRow + r; if (arow >= M) arow = M - 1;   // clamp (tail rows discarded at store)

    unsigned short* AsWaveBase = &As[wave * 512];           // wave*64 lanes*16B, in halfwords

    for (int k0 = 0; k0 < K; k0 += 32) {
        // ---- stage A (64x32) ----
        if constexpr (ABF16) {
            const unsigned short* A = (const unsigned short*)Avoid;
            gload_lds16(A + (size_t)arow * K + k0 + kq * 8, AsWaveBase);
        } else {
            const float* A = (const float*)Avoid;
            const float* p = A + (size_t)arow * K + k0 + kq * 8;
            float4 a0 = *(const float4*)p, a1 = *(const float4*)(p + 4);
            unsigned short h[8] = {f2bf(a0.x), f2bf(a0.y), f2bf(a0.z), f2bf(a0.w),
                                   f2bf(a1.x), f2bf(a1.y), f2bf(a1.z), f2bf(a1.w)};
            *(uint4*)&As[r * 32 + kq * 8] = *(uint4*)h;
        }
        // ---- stage B (256x32) via DMA, 4 passes of 64 cols ----
#pragma unroll
        for (int pass = 0; pass < 4; ++pass) {
            int bcol = r + pass * 64;
            gload_lds16(Bt + (size_t)bcol * K + k0 + kq * 8,
                        &Bs[(pass * 256 + wave * 64) * 8]);
        }
        __syncthreads();
        // ---- compute: 4 a-frags x 4 b-frags ----
        bf16x8 af[4];
#pragma unroll
        for (int i = 0; i < 4; ++i)
            af[i] = *(const bf16x8*)&As[(i * 16 + mrow) * 32 + quad * 8];
#pragma unroll
        for (int j = 0; j < 4; ++j) {
            bf16x8 bf = *(const bf16x8*)&Bs[(wave * 64 + j * 16 + mrow) * 32 + quad * 8];
#pragma unroll
            for (int i = 0; i < 4; ++i)
                acc[i][j] = __builtin_amdgcn_mfma_f32_16x16x32_bf16(af[i], bf, acc[i][j], 0, 0, 0);
        }
        __syncthreads();
    }
    // ---- epilogue: C/D layout col=lane&15, row=quad*4+v ----
#pragma unroll
    for (int i = 0; i < 4; ++i)
#pragma unroll
        for (int j = 0; j < 4; ++j) {
            int colo = wave * 64 + j * 16 + mrow;
#pragma unroll
            for (int v = 0; v < 4; ++v) {
                int row = blockRow + i * 16 + quad * 4 + v;
                if (row < M) C[(size_t)row * HID_F + colo] = f2bf(acc[i][j][v]);
            }
        }
}

// ---------------- aggregation (gather, CSR), bf16 m, fp32 accumulate ----------------

__global__ void agg_relu(const unsigned short* __restrict__ m, const int* __restrict__ row_ptr,
                         const int* __restrict__ col, const float* __restrict__ val,
                         const float* __restrict__ bias, unsigned short* __restrict__ hidden) {
    int i = blockIdx.x, l = threadIdx.x, c0 = l << 2;
    int p0 = row_ptr[i], p1 = row_ptr[i + 1];
    float a0 = 0.f, a1 = 0.f, a2 = 0.f, a3 = 0.f;
    for (int p = p0; p < p1; ++p) {
        int s = col[p]; float w = val[p];
        ushort4 u = *(const ushort4*)(m + (size_t)s * HID_F + c0);
        a0 = fmaf(bf2f(u.x), w, a0);
        a1 = fmaf(bf2f(u.y), w, a1);
        a2 = fmaf(bf2f(u.z), w, a2);
        a3 = fmaf(bf2f(u.w), w, a3);
    }
    float4 b = *(const float4*)(bias + c0);
    a0 = fmaxf(a0 + b.x, 0.f); a1 = fmaxf(a1 + b.y, 0.f);
    a2 = fmaxf(a2 + b.z, 0.f); a3 = fmaxf(a3 + b.w, 0.f);
    ushort4 o = make_ushort4(f2bf(a0), f2bf(a1), f2bf(a2), f2bf(a3));
    *(ushort4*)(hidden + (size_t)i * HID_F + c0) = o;
}

__global__ void agg_out(const unsigned short* __restrict__ m, const int* __restrict__ row_ptr,
                        const int* __restrict__ col, const float* __restrict__ val,
                        const float* __restrict__ bmu, const float* __restrict__ blv,
                        float* __restrict__ out, int N) {
    int i = blockIdx.x, l = threadIdx.x, c0 = l << 2;
    int p0 = row_ptr[i], p1 = row_ptr[i + 1];
    float a0 = 0.f, a1 = 0.f, a2 = 0.f, a3 = 0.f;
    for (int p = p0; p < p1; ++p) {
        int s = col[p]; float w = val[p];
        ushort4 u = *(const ushort4*)(m + (size_t)s * HID_F + c0);
        a0 = fmaf(bf2f(u.x), w, a0);
        a1 = fmaf(bf2f(u.y), w, a1);
        a2 = fmaf(bf2f(u.z), w, a2);
        a3 = fmaf(bf2f(u.w), w, a3);
    }
    if (l < 32) {
        float4 b = *(const float4*)(bmu + c0);
        float4 o = make_float4(a0 + b.x, a1 + b.y, a2 + b.z, a3 + b.w);
        *(float4*)(out + (size_t)i * LAT_F + c0) = o;
    } else {
        int c = c0 - 128;
        float4 b = *(const float4*)(blv + c);
        float4 o = make_float4(a0 + b.x, a1 + b.y, a2 + b.z, a3 + b.w);
        *(float4*)(out + (size_t)(N + i) * LAT_F + c) = o;
    }
}

// ---------------- launch ----------------

extern "C" void kernel_launch(void* const* d_in, const int* in_sizes, int n_in,
                              void* d_out, int out_size, void* d_ws, size_t ws_size,
                              hipStream_t stream) {
    const float* x    = (const float*)d_in[0];
    const int*   ei   = (const int*)d_in[1];
    const float* attr = (const float*)d_in[2];
    const float* W1   = (const float*)d_in[3];
    const float* b1   = (const float*)d_in[4];
    const float* Wmu  = (const float*)d_in[5];
    const float* bmu  = (const float*)d_in[6];
    const float* Wlv  = (const float*)d_in[7];
    const float* blv  = (const float*)d_in[8];
    float* out = (float*)d_out;

    const int N  = in_sizes[0] / IN_F;   // 50000
    const int E  = in_sizes[2];          // 800000
    const int EN = E + N;

    char* w = (char*)d_ws;
    size_t off = 0;
    auto carve = [&](size_t bytes) -> void* {
        void* p = w + off; off += (bytes + 255) & ~(size_t)255; return p;
    };
    float*          deg       = (float*)carve((size_t)N * 4);
    float*          dis       = (float*)carve((size_t)N * 4);
    int*            counts    = (int*)  carve((size_t)N * 4);
    int*            fill      = (int*)  carve((size_t)N * 4);
    int*            row_ptr   = (int*)  carve((size_t)(N + 1) * 4);
    int*            blockSums = (int*)  carve(64 * 4);
    int*            col       = (int*)  carve((size_t)EN * 4);
    float*          val       = (float*)carve((size_t)EN * 4);
    unsigned short* W1t       = (unsigned short*)carve((size_t)HID_F * IN_F * 2);
    unsigned short* B2t       = (unsigned short*)carve((size_t)HID_F * HID_F * 2);
    unsigned short* m         = (unsigned short*)carve((size_t)N * HID_F * 2);  // m1, reused as m2
    unsigned short* hidden    = (unsigned short*)carve((size_t)N * HID_F * 2);

    int nb256 = (N + 255) / 256;
    init_nodes<<<nb256, 256, 0, stream>>>(deg, counts, fill, N);
    edge_deg<<<(E + 255) / 256, 256, 0, stream>>>(ei, attr, deg, counts, E);
    node_dis<<<nb256, 256, 0, stream>>>(deg, dis, N);

    int NB = (N + 1023) / 1024;
    scan_blocks<<<NB, 256, 0, stream>>>(counts, row_ptr, blockSums, N);
    scan_sums<<<1, 64, 0, stream>>>(blockSums, NB);
    scan_add<<<NB, 256, 0, stream>>>(row_ptr, blockSums, N, EN);

    fill_csr<<<(EN + 255) / 256, 256, 0, stream>>>(ei, attr, dis, row_ptr, fill, col, val, E, N);

    prep_w1<<<(HID_F * IN_F + 255) / 256, 256, 0, stream>>>(W1, W1t);
    prep_b2<<<(HID_F * HID_F + 255) / 256, 256, 0, stream>>>(Wmu, Wlv, B2t);

    int gblocks = (N + 63) / 64;
    // m1 = bf16(x) @ W1   [50000,512]x[512,256] -> bf16
    gemm_mfma<false><<<gblocks, 256, 0, stream>>>(x, W1t, m, N, IN_F);
    // hidden = relu(A_hat * m1 + b1) -> bf16
    agg_relu<<<N, 64, 0, stream>>>(m, row_ptr, col, val, b1, hidden);
    // m2 = hidden @ [W_mu | W_lv]   [50000,256]x[256,256] -> bf16
    gemm_mfma<true><<<gblocks, 256, 0, stream>>>(hidden, B2t, m, N, HID_F);
    // (mu|logvar) = A_hat * m2 + (b_mu|b_lv) -> fp32 d_out
    agg_out<<<N, 64, 0, stream>>>(m, row_ptr, col, val, bmu, blv, out, N);
}

// Round 4
// 440.019 us; speedup vs baseline: 2.0842x; 1.1409x over previous
//
#include <hip/hip_runtime.h>

#define IN_F 512
#define HID_F 256
#define LAT_F 128

typedef __bf16 bf16x8 __attribute__((ext_vector_type(8)));
typedef float floatx4 __attribute__((ext_vector_type(4)));

#define FIX_SCALE 1048576.0f   // 2^20 fixed-point for degree accumulation

__device__ __forceinline__ unsigned short f2bf(float f) {
    union { float f; unsigned u; } v; v.f = f;
    unsigned r = (v.u + 0x7fff + ((v.u >> 16) & 1)) >> 16;
    return (unsigned short)r;
}
__device__ __forceinline__ float bf2f(unsigned short h) {
    union { unsigned u; float f; } v; v.u = ((unsigned)h) << 16;
    return v.f;
}

// async 16B global -> LDS DMA (dest = wave-uniform base + lane*16)
__device__ __forceinline__ void gload_lds16(const void* g, void* lds) {
    __builtin_amdgcn_global_load_lds(
        (const __attribute__((address_space(1))) unsigned int*)(uintptr_t)g,
        (__attribute__((address_space(3))) unsigned int*)(uintptr_t)lds,
        16, 0, 0);
}

// ---------------- fused prep: packed init + weight transpose/bf16 ----------------
// grid covers max(N, 256*512) = 131072 threads.

__global__ void prep_all(const float* __restrict__ W1, const float* __restrict__ Wmu,
                         const float* __restrict__ Wlv, unsigned long long* __restrict__ packed,
                         unsigned short* __restrict__ W1t, unsigned short* __restrict__ B2t,
                         int N) {
    int t = blockIdx.x * 256 + threadIdx.x;
    if (t < N) packed[t] = (1ULL << 32) | (unsigned long long)(unsigned)FIX_SCALE;  // count=1, w=1.0
    if (t < HID_F * IN_F) {            // W1t[n][k] = bf16(W1[k][n])
        int n = t >> 9, k = t & 511;
        W1t[t] = f2bf(W1[(size_t)k * HID_F + n]);
    }
    if (t < HID_F * HID_F) {           // B2t[n][k] = bf16([Wmu|Wlv][k][n])
        int n = t >> 8, k = t & 255;
        float v = (n < 128) ? Wmu[(size_t)k * LAT_F + n] : Wlv[(size_t)k * LAT_F + (n - 128)];
        B2t[t] = f2bf(v);
    }
}

// ---------------- degree pass: ONE u64 atomic per edge; returns CSR slot ----------------

__global__ void edge_deg(const int* __restrict__ ei, const float* __restrict__ attr,
                         unsigned long long* __restrict__ packed, int* __restrict__ slot, int E) {
    int e = blockIdx.x * 256 + threadIdx.x;
    if (e < E) {
        int d = ei[E + e];
        unsigned fw = __float2uint_rn(attr[e] * FIX_SCALE);
        unsigned long long old = atomicAdd(&packed[d], (1ULL << 32) | (unsigned long long)fw);
        slot[e] = (int)(old >> 32);    // count before increment (self-loop holds slot 0)
    }
}

__global__ void node_dis(const unsigned long long* __restrict__ packed,
                         float* __restrict__ dis, int* __restrict__ counts, int N) {
    int i = blockIdx.x * 256 + threadIdx.x;
    if (i < N) {
        unsigned long long p = packed[i];
        counts[i] = (int)(p >> 32);
        float dg = (float)(unsigned)(p & 0xffffffffu) * (1.0f / FIX_SCALE);
        dis[i] = dg > 0.f ? rsqrtf(fmaxf(dg, 1e-12f)) : 0.f;
    }
}

// ---------------- exclusive scan (counts -> row_ptr) ----------------

__global__ void scan_blocks(const int* __restrict__ counts, int* __restrict__ excl,
                            int* __restrict__ blockSums, int N) {
    __shared__ int sdata[256];
    int tid = threadIdx.x;
    int base = blockIdx.x * 1024 + tid * 4;
    int v[4]; int sum = 0;
#pragma unroll
    for (int j = 0; j < 4; ++j) { v[j] = (base + j < N) ? counts[base + j] : 0; sum += v[j]; }
    sdata[tid] = sum;
    __syncthreads();
    for (int off = 1; off < 256; off <<= 1) {
        int t = (tid >= off) ? sdata[tid - off] : 0;
        __syncthreads();
        sdata[tid] += t;
        __syncthreads();
    }
    if (tid == 255) blockSums[blockIdx.x] = sdata[255];
    int run = sdata[tid] - sum;
#pragma unroll
    for (int j = 0; j < 4; ++j) { if (base + j < N) excl[base + j] = run; run += v[j]; }
}

__global__ void scan_sums(int* blockSums, int NB) {
    __shared__ int s[64];
    int tid = threadIdx.x;
    int v = (tid < NB) ? blockSums[tid] : 0;
    s[tid] = v;
    __syncthreads();
    for (int off = 1; off < 64; off <<= 1) {
        int t = (tid >= off) ? s[tid - off] : 0;
        __syncthreads();
        s[tid] += t;
        __syncthreads();
    }
    if (tid < NB) blockSums[tid] = s[tid] - v;
}

__global__ void scan_add(int* row_ptr, const int* __restrict__ blockSums, int N, int total) {
    int tid = threadIdx.x;
    int base = blockIdx.x * 1024 + tid * 4;
    int add = blockSums[blockIdx.x];
#pragma unroll
    for (int j = 0; j < 4; ++j) if (base + j < N) row_ptr[base + j] += add;
    if (blockIdx.x == 0 && tid == 0) row_ptr[N] = total;
}

// ---------------- CSR fill (NO atomics — slots precomputed) ----------------

__global__ void fill_csr(const int* __restrict__ ei, const float* __restrict__ attr,
                         const int* __restrict__ slot, const float* __restrict__ dis,
                         const int* __restrict__ row_ptr,
                         int* __restrict__ col, float* __restrict__ val, int E, int N) {
    int e = blockIdx.x * 256 + threadIdx.x;
    if (e >= E + N) return;
    int s, d, sl; float w;
    if (e < E) { s = ei[e]; d = ei[E + e]; w = attr[e]; sl = slot[e]; }
    else       { s = d = e - E; w = 1.0f; sl = 0; }
    int pos = row_ptr[d] + sl;
    col[pos] = s;
    val[pos] = dis[s] * w * dis[d];
}

// ---------------- MFMA bf16 GEMM: C[M,256] = A[M,K] @ Bt[256,K]^T, C bf16 ----------------

template <bool ABF16>
__global__ __launch_bounds__(256) void gemm_mfma(const void* __restrict__ Avoid,
                                                 const unsigned short* __restrict__ Bt,
                                                 unsigned short* __restrict__ C,
                                                 int M, int K) {
    __shared__ unsigned short As[64 * 32];    // 4 KB
    __shared__ unsigned short Bs[256 * 32];   // 16 KB
    int tid = threadIdx.x;
    int wave = tid >> 6, lane = tid & 63;
    int mrow = lane & 15, quad = lane >> 4;
    int blockRow = blockIdx.x * 64;

    floatx4 acc[4][4];
#pragma unroll
    for (int i = 0; i < 4; ++i)
#pragma unroll
        for (int j = 0; j < 4; ++j) acc[i][j] = (floatx4){0.f, 0.f, 0.f, 0.f};

    int r = tid >> 2;            // 0..63 : A row / B col-mod-64
    int kq = tid & 3;            // 16B chunk within the 32-halfword k-slab
    int arow = blockRow + r; if (arow >= M) arow = M - 1;   // clamp (tail rows discarded at store)

    unsigned short* AsWaveBase = &As[wave * 512];

    for (int k0 = 0; k0 < K; k0 += 32) {
        if constexpr (ABF16) {
            const unsigned short* A = (const unsigned short*)Avoid;
            gload_lds16(A + (size_t)arow * K + k0 + kq * 8, AsWaveBase);
        } else {
            const float* A = (const float*)Avoid;
            const float* p = A + (size_t)arow * K + k0 + kq * 8;
            float4 a0 = *(const float4*)p, a1 = *(const float4*)(p + 4);
            unsigned short h[8] = {f2bf(a0.x), f2bf(a0.y), f2bf(a0.z), f2bf(a0.w),
                                   f2bf(a1.x), f2bf(a1.y), f2bf(a1.z), f2bf(a1.w)};
            *(uint4*)&As[r * 32 + kq * 8] = *(uint4*)h;
        }
#pragma unroll
        for (int pass = 0; pass < 4; ++pass) {
            int bcol = r + pass * 64;
            gload_lds16(Bt + (size_t)bcol * K + k0 + kq * 8,
                        &Bs[(pass * 256 + wave * 64) * 8]);
        }
        __syncthreads();
        bf16x8 af[4];
#pragma unroll
        for (int i = 0; i < 4; ++i)
            af[i] = *(const bf16x8*)&As[(i * 16 + mrow) * 32 + quad * 8];
#pragma unroll
        for (int j = 0; j < 4; ++j) {
            bf16x8 bf = *(const bf16x8*)&Bs[(wave * 64 + j * 16 + mrow) * 32 + quad * 8];
#pragma unroll
            for (int i = 0; i < 4; ++i)
                acc[i][j] = __builtin_amdgcn_mfma_f32_16x16x32_bf16(af[i], bf, acc[i][j], 0, 0, 0);
        }
        __syncthreads();
    }
#pragma unroll
    for (int i = 0; i < 4; ++i)
#pragma unroll
        for (int j = 0; j < 4; ++j) {
            int colo = wave * 64 + j * 16 + mrow;
#pragma unroll
            for (int v = 0; v < 4; ++v) {
                int row = blockRow + i * 16 + quad * 4 + v;
                if (row < M) C[(size_t)row * HID_F + colo] = f2bf(acc[i][j][v]);
            }
        }
}

// ---------------- aggregation (gather, CSR), bf16 m, fp32 accumulate ----------------

__global__ void agg_relu(const unsigned short* __restrict__ m, const int* __restrict__ row_ptr,
                         const int* __restrict__ col, const float* __restrict__ val,
                         const float* __restrict__ bias, unsigned short* __restrict__ hidden) {
    int i = blockIdx.x, l = threadIdx.x, c0 = l << 2;
    int p0 = row_ptr[i], p1 = row_ptr[i + 1];
    float a0 = 0.f, a1 = 0.f, a2 = 0.f, a3 = 0.f;
    for (int p = p0; p < p1; ++p) {
        int s = col[p]; float w = val[p];
        ushort4 u = *(const ushort4*)(m + (size_t)s * HID_F + c0);
        a0 = fmaf(bf2f(u.x), w, a0);
        a1 = fmaf(bf2f(u.y), w, a1);
        a2 = fmaf(bf2f(u.z), w, a2);
        a3 = fmaf(bf2f(u.w), w, a3);
    }
    float4 b = *(const float4*)(bias + c0);
    a0 = fmaxf(a0 + b.x, 0.f); a1 = fmaxf(a1 + b.y, 0.f);
    a2 = fmaxf(a2 + b.z, 0.f); a3 = fmaxf(a3 + b.w, 0.f);
    ushort4 o = make_ushort4(f2bf(a0), f2bf(a1), f2bf(a2), f2bf(a3));
    *(ushort4*)(hidden + (size_t)i * HID_F + c0) = o;
}

__global__ void agg_out(const unsigned short* __restrict__ m, const int* __restrict__ row_ptr,
                        const int* __restrict__ col, const float* __restrict__ val,
                        const float* __restrict__ bmu, const float* __restrict__ blv,
                        float* __restrict__ out, int N) {
    int i = blockIdx.x, l = threadIdx.x, c0 = l << 2;
    int p0 = row_ptr[i], p1 = row_ptr[i + 1];
    float a0 = 0.f, a1 = 0.f, a2 = 0.f, a3 = 0.f;
    for (int p = p0; p < p1; ++p) {
        int s = col[p]; float w = val[p];
        ushort4 u = *(const ushort4*)(m + (size_t)s * HID_F + c0);
        a0 = fmaf(bf2f(u.x), w, a0);
        a1 = fmaf(bf2f(u.y), w, a1);
        a2 = fmaf(bf2f(u.z), w, a2);
        a3 = fmaf(bf2f(u.w), w, a3);
    }
    if (l < 32) {
        float4 b = *(const float4*)(bmu + c0);
        float4 o = make_float4(a0 + b.x, a1 + b.y, a2 + b.z, a3 + b.w);
        *(float4*)(out + (size_t)i * LAT_F + c0) = o;
    } else {
        int c = c0 - 128;
        float4 b = *(const float4*)(blv + c);
        float4 o = make_float4(a0 + b.x, a1 + b.y, a2 + b.z, a3 + b.w);
        *(float4*)(out + (size_t)(N + i) * LAT_F + c) = o;
    }
}

// ---------------- launch ----------------

extern "C" void kernel_launch(void* const* d_in, const int* in_sizes, int n_in,
                              void* d_out, int out_size, void* d_ws, size_t ws_size,
                              hipStream_t stream) {
    const float* x    = (const float*)d_in[0];
    const int*   ei   = (const int*)d_in[1];
    const float* attr = (const float*)d_in[2];
    const float* W1   = (const float*)d_in[3];
    const float* b1   = (const float*)d_in[4];
    const float* Wmu  = (const float*)d_in[5];
    const float* bmu  = (const float*)d_in[6];
    const float* Wlv  = (const float*)d_in[7];
    const float* blv  = (const float*)d_in[8];
    float* out = (float*)d_out;

    const int N  = in_sizes[0] / IN_F;   // 50000
    const int E  = in_sizes[2];          // 800000
    const int EN = E + N;

    char* w = (char*)d_ws;
    size_t off = 0;
    auto carve = [&](size_t bytes) -> void* {
        void* p = w + off; off += (bytes + 255) & ~(size_t)255; return p;
    };
    unsigned long long* packed = (unsigned long long*)carve((size_t)N * 8);
    float*          dis       = (float*)carve((size_t)N * 4);
    int*            counts    = (int*)  carve((size_t)N * 4);
    int*            row_ptr   = (int*)  carve((size_t)(N + 1) * 4);
    int*            blockSums = (int*)  carve(64 * 4);
    int*            slot      = (int*)  carve((size_t)E * 4);
    int*            col       = (int*)  carve((size_t)EN * 4);
    float*          val       = (float*)carve((size_t)EN * 4);
    unsigned short* W1t       = (unsigned short*)carve((size_t)HID_F * IN_F * 2);
    unsigned short* B2t       = (unsigned short*)carve((size_t)HID_F * HID_F * 2);
    unsigned short* m         = (unsigned short*)carve((size_t)N * HID_F * 2);  // m1, reused as m2
    unsigned short* hidden    = (unsigned short*)carve((size_t)N * HID_F * 2);

    // prep: packed init + both weight transposes in one launch
    prep_all<<<(HID_F * IN_F + 255) / 256, 256, 0, stream>>>(W1, Wmu, Wlv, packed, W1t, B2t, N);

    edge_deg<<<(E + 255) / 256, 256, 0, stream>>>(ei, attr, packed, slot, E);
    node_dis<<<(N + 255) / 256, 256, 0, stream>>>(packed, dis, counts, N);

    int NB = (N + 1023) / 1024;
    scan_blocks<<<NB, 256, 0, stream>>>(counts, row_ptr, blockSums, N);
    scan_sums<<<1, 64, 0, stream>>>(blockSums, NB);
    scan_add<<<NB, 256, 0, stream>>>(row_ptr, blockSums, N, EN);

    fill_csr<<<(EN + 255) / 256, 256, 0, stream>>>(ei, attr, slot, dis, row_ptr, col, val, E, N);

    int gblocks = (N + 63) / 64;
    // m1 = bf16(x) @ W1   [50000,512]x[512,256] -> bf16
    gemm_mfma<false><<<gblocks, 256, 0, stream>>>(x, W1t, m, N, IN_F);
    // hidden = relu(A_hat * m1 + b1) -> bf16
    agg_relu<<<N, 64, 0, stream>>>(m, row_ptr, col, val, b1, hidden);
    // m2 = hidden @ [W_mu | W_lv]   [50000,256]x[256,256] -> bf16
    gemm_mfma<true><<<gblocks, 256, 0, stream>>>(hidden, B2t, m, N, HID_F);
    // (mu|logvar) = A_hat * m2 + (b_mu|b_lv) -> fp32 d_out
    agg_out<<<N, 64, 0, stream>>>(m, row_ptr, col, val, bmu, blv, out, N);
}

// Round 5
// 430.689 us; speedup vs baseline: 2.1294x; 1.0217x over previous
//
#include <hip/hip_runtime.h>

#define IN_F 512
#define HID_F 256
#define LAT_F 128

typedef __bf16 bf16x8 __attribute__((ext_vector_type(8)));
typedef float floatx4 __attribute__((ext_vector_type(4)));

#define FIX_SCALE 1048576.0f   // 2^20 fixed-point for degree accumulation

__device__ __forceinline__ unsigned short f2bf(float f) {
    union { float f; unsigned u; } v; v.f = f;
    unsigned r = (v.u + 0x7fff + ((v.u >> 16) & 1)) >> 16;
    return (unsigned short)r;
}
__device__ __forceinline__ float bf2f(unsigned short h) {
    union { unsigned u; float f; } v; v.u = ((unsigned)h) << 16;
    return v.f;
}

// async 16B global -> LDS DMA (dest = wave-uniform base + lane*16)
__device__ __forceinline__ void gload_lds16(const void* g, void* lds) {
    __builtin_amdgcn_global_load_lds(
        (const __attribute__((address_space(1))) unsigned int*)(uintptr_t)g,
        (__attribute__((address_space(3))) unsigned int*)(uintptr_t)lds,
        16, 0, 0);
}

// ---------------- fused prep: packed init + weight transpose/bf16 ----------------

__global__ void prep_all(const float* __restrict__ W1, const float* __restrict__ Wmu,
                         const float* __restrict__ Wlv, unsigned long long* __restrict__ packed,
                         unsigned short* __restrict__ W1t, unsigned short* __restrict__ B2t,
                         int N) {
    int t = blockIdx.x * 256 + threadIdx.x;
    if (t < N) packed[t] = (1ULL << 32) | (unsigned long long)(unsigned)FIX_SCALE;  // count=1, w=1.0
    if (t < HID_F * IN_F) {            // W1t[n][k] = bf16(W1[k][n])
        int n = t >> 9, k = t & 511;
        W1t[t] = f2bf(W1[(size_t)k * HID_F + n]);
    }
    if (t < HID_F * HID_F) {           // B2t[n][k] = bf16([Wmu|Wlv][k][n])
        int n = t >> 8, k = t & 255;
        float v = (n < 128) ? Wmu[(size_t)k * LAT_F + n] : Wlv[(size_t)k * LAT_F + (n - 128)];
        B2t[t] = f2bf(v);
    }
}

// ---------------- degree pass: ONE u64 atomic per edge; returns CSR slot ----------------

__global__ void edge_deg(const int* __restrict__ ei, const float* __restrict__ attr,
                         unsigned long long* __restrict__ packed, int* __restrict__ slot, int E) {
    int e = blockIdx.x * 256 + threadIdx.x;
    if (e < E) {
        int d = ei[E + e];
        unsigned fw = __float2uint_rn(attr[e] * FIX_SCALE);
        unsigned long long old = atomicAdd(&packed[d], (1ULL << 32) | (unsigned long long)fw);
        slot[e] = (int)(old >> 32);    // count before increment (self-loop holds slot 0)
    }
}

// ---------------- scan pass 1 (fused with dis computation) ----------------

__global__ void scan_blocks(const unsigned long long* __restrict__ packed,
                            float* __restrict__ dis, int* __restrict__ excl,
                            int* __restrict__ blockSums, int N) {
    __shared__ int sdata[256];
    int tid = threadIdx.x;
    int base = blockIdx.x * 1024 + tid * 4;
    int v[4]; int sum = 0;
#pragma unroll
    for (int j = 0; j < 4; ++j) {
        int c = 0;
        if (base + j < N) {
            unsigned long long p = packed[base + j];
            c = (int)(p >> 32);
            float dg = (float)(unsigned)(p & 0xffffffffu) * (1.0f / FIX_SCALE);
            dis[base + j] = dg > 0.f ? rsqrtf(fmaxf(dg, 1e-12f)) : 0.f;
        }
        v[j] = c; sum += c;
    }
    sdata[tid] = sum;
    __syncthreads();
    for (int off = 1; off < 256; off <<= 1) {
        int t = (tid >= off) ? sdata[tid - off] : 0;
        __syncthreads();
        sdata[tid] += t;
        __syncthreads();
    }
    if (tid == 255) blockSums[blockIdx.x] = sdata[255];
    int run = sdata[tid] - sum;
#pragma unroll
    for (int j = 0; j < 4; ++j) { if (base + j < N) excl[base + j] = run; run += v[j]; }
}

__global__ void scan_sums(int* blockSums, int NB) {
    __shared__ int s[64];
    int tid = threadIdx.x;
    int v = (tid < NB) ? blockSums[tid] : 0;
    s[tid] = v;
    __syncthreads();
    for (int off = 1; off < 64; off <<= 1) {
        int t = (tid >= off) ? s[tid - off] : 0;
        __syncthreads();
        s[tid] += t;
        __syncthreads();
    }
    if (tid < NB) blockSums[tid] = s[tid] - v;
}

__global__ void scan_add(int* row_ptr, const int* __restrict__ blockSums, int N, int total) {
    int tid = threadIdx.x;
    int base = blockIdx.x * 1024 + tid * 4;
    int add = blockSums[blockIdx.x];
#pragma unroll
    for (int j = 0; j < 4; ++j) if (base + j < N) row_ptr[base + j] += add;
    if (blockIdx.x == 0 && tid == 0) row_ptr[N] = total;
}

// ---------------- CSR fill (NO atomics — slots precomputed) ----------------

__global__ void fill_csr(const int* __restrict__ ei, const float* __restrict__ attr,
                         const int* __restrict__ slot, const float* __restrict__ dis,
                         const int* __restrict__ row_ptr,
                         int* __restrict__ col, float* __restrict__ val, int E, int N) {
    int e = blockIdx.x * 256 + threadIdx.x;
    if (e >= E + N) return;
    int s, d, sl; float w;
    if (e < E) { s = ei[e]; d = ei[E + e]; w = attr[e]; sl = slot[e]; }
    else       { s = d = e - E; w = 1.0f; sl = 0; }
    int pos = row_ptr[d] + sl;
    col[pos] = s;
    val[pos] = dis[s] * w * dis[d];
}

// ---------------- MFMA bf16 GEMM, software-pipelined (1 barrier / k-step) ----------------
// C[M,256] = A[M,K] @ Bt[256,K]^T, C bf16. BM=64, BN=256, BK=32; 4 waves;
// wave w owns 64 rows x cols [64w,64w+64) as a 4x4 grid of 16x16x32 MFMA tiles.
// Double-buffered LDS; prefetch issued AFTER the barrier so its drain applies to
// loads issued one full compute phase earlier.

template <bool ABF16>
__global__ __launch_bounds__(256) void gemm_mfma(const void* __restrict__ Avoid,
                                                 const unsigned short* __restrict__ Bt,
                                                 unsigned short* __restrict__ C,
                                                 int M, int K) {
    __shared__ unsigned short As[2][64 * 32];    // 2 x 4 KB
    __shared__ unsigned short Bs[2][256 * 32];   // 2 x 16 KB
    int tid = threadIdx.x;
    int wave = tid >> 6, lane = tid & 63;
    int mrow = lane & 15, quad = lane >> 4;
    int blockRow = blockIdx.x * 64;

    const unsigned short* Abf = (const unsigned short*)Avoid;
    const float*          Afp = (const float*)Avoid;

    floatx4 acc[4][4];
#pragma unroll
    for (int i = 0; i < 4; ++i)
#pragma unroll
        for (int j = 0; j < 4; ++j) acc[i][j] = (floatx4){0.f, 0.f, 0.f, 0.f};

    int r = tid >> 2;            // 0..63 : A row / B col-mod-64
    int kq = tid & 3;            // 16B chunk within the 32-halfword k-slab
    int arow = blockRow + r; if (arow >= M) arow = M - 1;   // clamp (tail rows discarded at store)

    // ---- prologue: stage k=0 into buffer 0 ----
    if constexpr (ABF16) {
        gload_lds16(Abf + (size_t)arow * K + kq * 8, &As[0][wave * 512]);
    } else {
        const float* p = Afp + (size_t)arow * K + kq * 8;
        float4 a0 = *(const float4*)p, a1 = *(const float4*)(p + 4);
        unsigned short h[8] = {f2bf(a0.x), f2bf(a0.y), f2bf(a0.z), f2bf(a0.w),
                               f2bf(a1.x), f2bf(a1.y), f2bf(a1.z), f2bf(a1.w)};
        *(uint4*)&As[0][r * 32 + kq * 8] = *(uint4*)h;
    }
#pragma unroll
    for (int pass = 0; pass < 4; ++pass)
        gload_lds16(Bt + (size_t)(r + pass * 64) * K + kq * 8,
                    &Bs[0][(pass * 256 + wave * 64) * 8]);

    int cur = 0;
    for (int k0 = 0; k0 < K; k0 += 32) {
        __syncthreads();   // drains prev-iteration prefetch: buf[cur] is ready
        int kn = k0 + 32;
        bool more = kn < K;
        float4 a0, a1;
        if (more) {
            // A first (so its consume waits vmcnt(4), leaving B prefetch in flight)
            if constexpr (ABF16) {
                gload_lds16(Abf + (size_t)arow * K + kn + kq * 8, &As[cur ^ 1][wave * 512]);
            } else {
                const float* p = Afp + (size_t)arow * K + kn + kq * 8;
                a0 = *(const float4*)p; a1 = *(const float4*)(p + 4);
            }
#pragma unroll
            for (int pass = 0; pass < 4; ++pass)
                gload_lds16(Bt + (size_t)(r + pass * 64) * K + kn + kq * 8,
                            &Bs[cur ^ 1][(pass * 256 + wave * 64) * 8]);
        }
        // ---- compute on buf[cur]: 4 a-frags x 4 b-frags ----
        bf16x8 af[4];
#pragma unroll
        for (int i = 0; i < 4; ++i)
            af[i] = *(const bf16x8*)&As[cur][(i * 16 + mrow) * 32 + quad * 8];
#pragma unroll
        for (int j = 0; j < 4; ++j) {
            bf16x8 bf = *(const bf16x8*)&Bs[cur][(wave * 64 + j * 16 + mrow) * 32 + quad * 8];
#pragma unroll
            for (int i = 0; i < 4; ++i)
                acc[i][j] = __builtin_amdgcn_mfma_f32_16x16x32_bf16(af[i], bf, acc[i][j], 0, 0, 0);
        }
        if (!ABF16 && more) {  // convert + stage next A after compute (load latency overlapped)
            unsigned short h[8] = {f2bf(a0.x), f2bf(a0.y), f2bf(a0.z), f2bf(a0.w),
                                   f2bf(a1.x), f2bf(a1.y), f2bf(a1.z), f2bf(a1.w)};
            *(uint4*)&As[cur ^ 1][r * 32 + kq * 8] = *(uint4*)h;
        }
        cur ^= 1;
    }
    // ---- epilogue: C/D layout col=lane&15, row=quad*4+v ----
#pragma unroll
    for (int i = 0; i < 4; ++i)
#pragma unroll
        for (int j = 0; j < 4; ++j) {
            int colo = wave * 64 + j * 16 + mrow;
#pragma unroll
            for (int v = 0; v < 4; ++v) {
                int row = blockRow + i * 16 + quad * 4 + v;
                if (row < M) C[(size_t)row * HID_F + colo] = f2bf(acc[i][j][v]);
            }
        }
}

// ---------------- aggregation (gather, CSR), bf16 m, fp32 accumulate ----------------

__global__ void agg_relu(const unsigned short* __restrict__ m, const int* __restrict__ row_ptr,
                         const int* __restrict__ col, const float* __restrict__ val,
                         const float* __restrict__ bias, unsigned short* __restrict__ hidden) {
    int i = blockIdx.x, l = threadIdx.x, c0 = l << 2;
    int p0 = row_ptr[i], p1 = row_ptr[i + 1];
    float a0 = 0.f, a1 = 0.f, a2 = 0.f, a3 = 0.f;
    for (int p = p0; p < p1; ++p) {
        int s = col[p]; float w = val[p];
        ushort4 u = *(const ushort4*)(m + (size_t)s * HID_F + c0);
        a0 = fmaf(bf2f(u.x), w, a0);
        a1 = fmaf(bf2f(u.y), w, a1);
        a2 = fmaf(bf2f(u.z), w, a2);
        a3 = fmaf(bf2f(u.w), w, a3);
    }
    float4 b = *(const float4*)(bias + c0);
    a0 = fmaxf(a0 + b.x, 0.f); a1 = fmaxf(a1 + b.y, 0.f);
    a2 = fmaxf(a2 + b.z, 0.f); a3 = fmaxf(a3 + b.w, 0.f);
    ushort4 o = make_ushort4(f2bf(a0), f2bf(a1), f2bf(a2), f2bf(a3));
    *(ushort4*)(hidden + (size_t)i * HID_F + c0) = o;
}

__global__ void agg_out(const unsigned short* __restrict__ m, const int* __restrict__ row_ptr,
                        const int* __restrict__ col, const float* __restrict__ val,
                        const float* __restrict__ bmu, const float* __restrict__ blv,
                        float* __restrict__ out, int N) {
    int i = blockIdx.x, l = threadIdx.x, c0 = l << 2;
    int p0 = row_ptr[i], p1 = row_ptr[i + 1];
    float a0 = 0.f, a1 = 0.f, a2 = 0.f, a3 = 0.f;
    for (int p = p0; p < p1; ++p) {
        int s = col[p]; float w = val[p];
        ushort4 u = *(const ushort4*)(m + (size_t)s * HID_F + c0);
        a0 = fmaf(bf2f(u.x), w, a0);
        a1 = fmaf(bf2f(u.y), w, a1);
        a2 = fmaf(bf2f(u.z), w, a2);
        a3 = fmaf(bf2f(u.w), w, a3);
    }
    if (l < 32) {
        float4 b = *(const float4*)(bmu + c0);
        float4 o = make_float4(a0 + b.x, a1 + b.y, a2 + b.z, a3 + b.w);
        *(float4*)(out + (size_t)i * LAT_F + c0) = o;
    } else {
        int c = c0 - 128;
        float4 b = *(const float4*)(blv + c);
        float4 o = make_float4(a0 + b.x, a1 + b.y, a2 + b.z, a3 + b.w);
        *(float4*)(out + (size_t)(N + i) * LAT_F + c) = o;
    }
}

// ---------------- launch ----------------

extern "C" void kernel_launch(void* const* d_in, const int* in_sizes, int n_in,
                              void* d_out, int out_size, void* d_ws, size_t ws_size,
                              hipStream_t stream) {
    const float* x    = (const float*)d_in[0];
    const int*   ei   = (const int*)d_in[1];
    const float* attr = (const float*)d_in[2];
    const float* W1   = (const float*)d_in[3];
    const float* b1   = (const float*)d_in[4];
    const float* Wmu  = (const float*)d_in[5];
    const float* bmu  = (const float*)d_in[6];
    const float* Wlv  = (const float*)d_in[7];
    const float* blv  = (const float*)d_in[8];
    float* out = (float*)d_out;

    const int N  = in_sizes[0] / IN_F;   // 50000
    const int E  = in_sizes[2];          // 800000
    const int EN = E + N;

    char* w = (char*)d_ws;
    size_t off = 0;
    auto carve = [&](size_t bytes) -> void* {
        void* p = w + off; off += (bytes + 255) & ~(size_t)255; return p;
    };
    unsigned long long* packed = (unsigned long long*)carve((size_t)N * 8);
    float*          dis       = (float*)carve((size_t)N * 4);
    int*            row_ptr   = (int*)  carve((size_t)(N + 1) * 4);
    int*            blockSums = (int*)  carve(64 * 4);
    int*            slot      = (int*)  carve((size_t)E * 4);
    int*            col       = (int*)  carve((size_t)EN * 4);
    float*          val       = (float*)carve((size_t)EN * 4);
    unsigned short* W1t       = (unsigned short*)carve((size_t)HID_F * IN_F * 2);
    unsigned short* B2t       = (unsigned short*)carve((size_t)HID_F * HID_F * 2);
    unsigned short* m         = (unsigned short*)carve((size_t)N * HID_F * 2);  // m1, reused as m2
    unsigned short* hidden    = (unsigned short*)carve((size_t)N * HID_F * 2);

    prep_all<<<(HID_F * IN_F + 255) / 256, 256, 0, stream>>>(W1, Wmu, Wlv, packed, W1t, B2t, N);

    edge_deg<<<(E + 255) / 256, 256, 0, stream>>>(ei, attr, packed, slot, E);

    int NB = (N + 1023) / 1024;
    scan_blocks<<<NB, 256, 0, stream>>>(packed, dis, row_ptr, blockSums, N);
    scan_sums<<<1, 64, 0, stream>>>(blockSums, NB);
    scan_add<<<NB, 256, 0, stream>>>(row_ptr, blockSums, N, EN);

    fill_csr<<<(EN + 255) / 256, 256, 0, stream>>>(ei, attr, slot, dis, row_ptr, col, val, E, N);

    int gblocks = (N + 63) / 64;
    // m1 = bf16(x) @ W1   [50000,512]x[512,256] -> bf16
    gemm_mfma<false><<<gblocks, 256, 0, stream>>>(x, W1t, m, N, IN_F);
    // hidden = relu(A_hat * m1 + b1) -> bf16
    agg_relu<<<N, 64, 0, stream>>>(m, row_ptr, col, val, b1, hidden);
    // m2 = hidden @ [W_mu | W_lv]   [50000,256]x[256,256] -> bf16
    gemm_mfma<true><<<gblocks, 256, 0, stream>>>(hidden, B2t, m, N, HID_F);
    // (mu|logvar) = A_hat * m2 + (b_mu|b_lv) -> fp32 d_out
    agg_out<<<N, 64, 0, stream>>>(m, row_ptr, col, val, bmu, blv, out, N);
}